// Round 1
// baseline (152.230 us; speedup 1.0000x reference)
//
#include <hip/hip_runtime.h>
#include <math.h>

#define HH 128
#define WW 128
#define HW (HH*WW)
#define BB 2
#define CC 14
#define NPAIR 26   // B * (C-1)

// ---------------------------------------------------------------------------
// ws layout (bytes):
//   ps    : [BB][HW] u8      @ 0          (32768)
//   pt    : [BB][HW] u8      @ 32768      (32768)
//   pred  : [NPAIR][HW] f32  @ 65536      (1703936)
//   targ  : [NPAIR][HW] u8   @ 1769472    (425984)
//   d1    : [4*NPAIR][HW] u8 @ 2195456    (1703936)
//   flags : [104] int        @ 3899392    (416)
//   sums  : [NPAIR] f32      @ 3899808    (104)
// total ~3.9 MB
// ---------------------------------------------------------------------------

__global__ void k_zero(int* __restrict__ flags, float* __restrict__ sums) {
    int t = threadIdx.x;
    if (t < 104) flags[t] = 0;
    if (t < NPAIR) sums[t] = 0.0f;
}

// argmax over channel dim for both student and teacher (first-max tie rule)
__global__ void k_argmax(const float* __restrict__ Ls, const float* __restrict__ Lt,
                         unsigned char* __restrict__ ps, unsigned char* __restrict__ pt) {
    int tid = blockIdx.x * blockDim.x + threadIdx.x;
    const int total = BB * HW;
    if (tid >= 2 * total) return;
    const float* L = (tid < total) ? Ls : Lt;
    unsigned char* dst = (tid < total) ? ps : pt;
    int p = (tid < total) ? tid : tid - total;
    int b = p / HW;
    int pix = p - b * HW;
    const float* base = L + (size_t)b * CC * HW + pix;
    float best = base[0];
    int bi = 0;
#pragma unroll
    for (int c = 1; c < CC; ++c) {
        float v = base[(size_t)c * HW];
        if (v > best) { best = v; bi = c; }   // strictly greater -> first index wins
    }
    dst[p] = (unsigned char)bi;
}

// edge masks (mask & ~binary_erosion, cross SE, border erodes) -> pred, targ
__global__ void k_masks(const float* __restrict__ Ls,
                        const unsigned char* __restrict__ ps,
                        const unsigned char* __restrict__ pt,
                        float* __restrict__ pred, unsigned char* __restrict__ targ) {
    int tid = blockIdx.x * blockDim.x + threadIdx.x;
    if (tid >= NPAIR * HW) return;
    int n = tid / HW;
    int pix = tid - n * HW;
    int b = n / (CC - 1);
    int c = 1 + (n - b * (CC - 1));
    int i = pix >> 7, j = pix & (WW - 1);

    const unsigned char* P = ps + b * HW;
    bool m = (P[pix] == c);
    bool er = m
        && (i > 0        && P[pix - WW] == c)
        && (i < HH - 1   && P[pix + WW] == c)
        && (j > 0        && P[pix - 1]  == c)
        && (j < WW - 1   && P[pix + 1]  == c);
    bool es = m && !er;
    pred[tid] = es ? Ls[((size_t)b * CC + c) * HW + pix] : 0.0f;

    const unsigned char* T = pt + b * HW;
    bool mt = (T[pix] == c);
    bool ert = mt
        && (i > 0        && T[pix - WW] == c)
        && (i < HH - 1   && T[pix + WW] == c)
        && (j > 0        && T[pix - 1]  == c)
        && (j < WW - 1   && T[pix + 1]  == c);
    bool et = mt && !ert;
    targ[tid] = et ? T[pix] : (unsigned char)0;
}

// per-column 1D distance transform (two scans). 104 maps = 26 pairs x
// {fgP, ~fgP, fgT, ~fgT}. sentinel 255 marks "no set pixel in this column".
__global__ void k_coledt(const float* __restrict__ pred, const unsigned char* __restrict__ targ,
                         unsigned char* __restrict__ d1, int* __restrict__ flags) {
    int m = blockIdx.x;          // 0..103
    int n = m >> 2, t = m & 3;
    int q = threadIdx.x;         // column, 0..127
    __shared__ unsigned char d1s[HH][WW];

    unsigned int setb[4] = {0u, 0u, 0u, 0u};
    if (t < 2) {
        const float* p = pred + (size_t)n * HW;
        for (int i = 0; i < HH; ++i) {
            bool fg = p[i * WW + q] > 0.5f;
            bool s = (t == 0) ? fg : !fg;
            if (s) setb[i >> 5] |= (1u << (i & 31));
        }
    } else {
        const unsigned char* p = targ + (size_t)n * HW;
        for (int i = 0; i < HH; ++i) {
            bool fg = p[i * WW + q] >= 1;
            bool s = (t == 2) ? fg : !fg;
            if (s) setb[i >> 5] |= (1u << (i & 31));
        }
    }

    int d = 255;
    for (int i = 0; i < HH; ++i) {
        bool s = (setb[i >> 5] >> (i & 31)) & 1u;
        d = s ? 0 : (d < 255 ? d + 1 : 255);
        d1s[i][q] = (unsigned char)d;
    }
    d = 255;
    for (int i = HH - 1; i >= 0; --i) {
        bool s = (setb[i >> 5] >> (i & 31)) & 1u;
        d = s ? 0 : (d < 255 ? d + 1 : 255);
        unsigned char prev = d1s[i][q];
        if (d < (int)prev) d1s[i][q] = (unsigned char)d;
    }

    if ((setb[0] | setb[1] | setb[2] | setb[3]) != 0u) atomicOr(&flags[m], 1);

    // coalesced write-out (each thread owns its column in LDS; rows are
    // written with consecutive q -> contiguous bytes)
    unsigned char* out = d1 + (size_t)m * HW;
    for (int i = 0; i < HH; ++i) out[i * WW + q] = d1s[i][q];
}

// per-row min_q d1^2 + (q-j)^2 for all 4 maps, then fused loss accumulation
__global__ void k_rowedt(const float* __restrict__ pred, const unsigned char* __restrict__ targ,
                         const unsigned char* __restrict__ d1, const int* __restrict__ flags,
                         float* __restrict__ sums) {
    int blk = blockIdx.x;        // n*128 + i
    int n = blk >> 7, i = blk & (HH - 1);
    int j = threadIdx.x;         // 0..127

    __shared__ int rowSq[4][WW]; // d1^2 per map for this row
    const size_t rowOff = (size_t)i * WW + j;
#pragma unroll
    for (int t = 0; t < 4; ++t) {
        int d = d1[((size_t)(4 * n + t)) * HW + rowOff];
        rowSq[t][j] = d * d;
    }
    __syncthreads();

    int b0 = 0x7fffffff, b1 = 0x7fffffff, b2 = 0x7fffffff, b3 = 0x7fffffff;
    for (int q = 0; q < WW; ++q) {
        int dq = q - j;
        int off = dq * dq;
        int v0 = rowSq[0][q] + off; if (v0 < b0) b0 = v0;
        int v1 = rowSq[1][q] + off; if (v1 < b1) b1 = v1;
        int v2 = rowSq[2][q] + off; if (v2 < b2) b2 = v2;
        int v3 = rowSq[3][q] + off; if (v3 < b3) b3 = v3;
    }

    bool vP = flags[4 * n + 0] && flags[4 * n + 1];
    bool vT = flags[4 * n + 2] && flags[4 * n + 3];
    float fieldP = vP ? (float)(b0 + b1) : 0.0f;
    float fieldT = vT ? (float)(b2 + b3) : 0.0f;

    float pv = pred[(size_t)n * HW + rowOff];
    float tv = (float)targ[(size_t)n * HW + rowOff];
    float diff = pv - tv;
    float v = diff * diff * (fieldP + fieldT);

    // block reduce: 2 waves of 64
    for (int o = 32; o > 0; o >>= 1) v += __shfl_down(v, o);
    __shared__ float wsum[2];
    int lane = j & 63, wid = j >> 6;
    if (lane == 0) wsum[wid] = v;
    __syncthreads();
    if (j == 0) atomicAdd(&sums[n], wsum[0] + wsum[1]);
}

__global__ void k_final(const float* __restrict__ sums, float* __restrict__ out) {
    if (blockIdx.x == 0 && threadIdx.x == 0) {
        float s = 0.0f;
        for (int n = 0; n < NPAIR; ++n) {
            float hd = sums[n] * (1.0f / (float)HW);
            s += logf(hd + 1.0f);
        }
        out[0] = 0.5f * s;   // (1 - LOSS_WEIGHT) * sum
    }
}

extern "C" void kernel_launch(void* const* d_in, const int* in_sizes, int n_in,
                              void* d_out, int out_size, void* d_ws, size_t ws_size,
                              hipStream_t stream) {
    const float* Ls = (const float*)d_in[0];
    const float* Lt = (const float*)d_in[1];
    float* out = (float*)d_out;

    char* w = (char*)d_ws;
    unsigned char* ps   = (unsigned char*)(w);
    unsigned char* pt   = (unsigned char*)(w + 32768);
    float*         pred = (float*)        (w + 65536);
    unsigned char* targ = (unsigned char*)(w + 1769472);
    unsigned char* d1   = (unsigned char*)(w + 2195456);
    int*           flags= (int*)          (w + 3899392);
    float*         sums = (float*)        (w + 3899808);

    k_zero<<<1, 128, 0, stream>>>(flags, sums);
    k_argmax<<<(2 * BB * HW + 255) / 256, 256, 0, stream>>>(Ls, Lt, ps, pt);
    k_masks<<<(NPAIR * HW + 255) / 256, 256, 0, stream>>>(Ls, ps, pt, pred, targ);
    k_coledt<<<4 * NPAIR, WW, 0, stream>>>(pred, targ, d1, flags);
    k_rowedt<<<NPAIR * HH, WW, 0, stream>>>(pred, targ, d1, flags, sums);
    k_final<<<1, 64, 0, stream>>>(sums, out);
}

// Round 2
// 146.729 us; speedup vs baseline: 1.0375x; 1.0375x over previous
//
#include <hip/hip_runtime.h>
#include <math.h>
#include <limits.h>

#define HH 128
#define WW 128
#define HW (HH*WW)
#define BB 2
#define CC 14
#define NPAIR 26   // B * (C-1)

// ---------------------------------------------------------------------------
// ws layout (bytes):
//   ps    : [BB][HW] u8          @ 0        (32768)
//   pt    : [BB][HW] u8          @ 32768    (32768)
//   cbP   : [NPAIR][WW] u64x2    @ 65536    (53248)   column fg-bitmasks, student
//   cbT   : [NPAIR][WW] u64x2    @ 118784   (53248)   column fg-bitmasks, teacher
//   flags : [NPAIR] int bitfield @ 172032   (104)     bit0 anyFgP,1 anyBgP,2 anyFgT,3 anyBgT
//   sums  : [NPAIR] f32          @ 172160   (104)
// ---------------------------------------------------------------------------

// edge = mask & ~erosion(mask), cross SE, border erodes (border_value=0)
__device__ inline bool edge_at(const unsigned char* __restrict__ M, int i, int j, int c) {
    int pix = i * WW + j;
    if (M[pix] != c) return false;
    bool er = (i > 0) && (M[pix - WW] == c)
           && (i < HH - 1) && (M[pix + WW] == c)
           && (j > 0) && (M[pix - 1] == c)
           && (j < WW - 1) && (M[pix + 1] == c);
    return !er;
}

// distance from position i (0..127) to nearest set bit in 128-bit mask {lo,hi};
// 255 if mask empty. i is wave-uniform (derived from blockIdx) -> cheap branches.
__device__ inline int nbd(unsigned long long lo, unsigned long long hi, int i) {
    int up = 255, down = 255;
    // bits p >= i, shifted so p==i lands at bit 0
    unsigned long long slo, shi;
    if (i == 0)      { slo = lo; shi = hi; }
    else if (i < 64) { slo = (lo >> i) | (hi << (64 - i)); shi = hi >> i; }
    else             { slo = hi >> (i - 64); shi = 0ULL; }
    if (slo)      up = __builtin_ctzll(slo);
    else if (shi) up = 64 + __builtin_ctzll(shi);
    // bits p <= i, shifted so p==i lands at bit 127
    int s = 127 - i;
    unsigned long long llo, lhi;
    if (s == 0)      { llo = lo; lhi = hi; }
    else if (s < 64) { lhi = (hi << s) | (lo >> (64 - s)); llo = lo << s; }
    else             { lhi = lo << (s - 64); llo = 0ULL; }
    if (lhi)      down = __builtin_clzll(lhi);
    else if (llo) down = 64 + __builtin_clzll(llo);
    return min(up, down);
}

// argmax over channels for student+teacher; block 0 also zeroes flags/sums
__global__ void k_argmax(const float* __restrict__ Ls, const float* __restrict__ Lt,
                         unsigned char* __restrict__ ps, unsigned char* __restrict__ pt,
                         int* __restrict__ flags, float* __restrict__ sums) {
    if (blockIdx.x == 0 && threadIdx.x < NPAIR) {
        flags[threadIdx.x] = 0;
        sums[threadIdx.x] = 0.0f;
    }
    int tid = blockIdx.x * blockDim.x + threadIdx.x;
    const int total = BB * HW;
    if (tid >= 2 * total) return;
    const float* L = (tid < total) ? Ls : Lt;
    unsigned char* dst = (tid < total) ? ps : pt;
    int p = (tid < total) ? tid : tid - total;
    int b = p / HW;
    int pix = p - b * HW;
    const float* base = L + (size_t)b * CC * HW + pix;
    float best = base[0];
    int bi = 0;
#pragma unroll
    for (int c = 1; c < CC; ++c) {
        float v = base[(size_t)c * HW];
        if (v > best) { best = v; bi = c; }   // first-max tie rule
    }
    dst[p] = (unsigned char)bi;
}

// build per-column 128-bit fg masks via ballot. block = (pair, column q),
// 128 threads = rows (2 waves: rows 0-63, 64-127). bg masks are complements.
__global__ void k_bits(const unsigned char* __restrict__ ps, const unsigned char* __restrict__ pt,
                       const float* __restrict__ Ls,
                       ulonglong2* __restrict__ cbP, ulonglong2* __restrict__ cbT,
                       int* __restrict__ flags) {
    int blk = blockIdx.x;          // n*WW + q
    int n = blk >> 7, q = blk & (WW - 1);
    int i = threadIdx.x;           // row
    int b = n / (CC - 1), c = 1 + (n - b * (CC - 1));

    bool es = edge_at(ps + b * HW, i, q, c);
    bool fgP = false;
    if (es) fgP = Ls[((size_t)(b * CC + c)) * HW + i * WW + q] > 0.5f;  // pred = es*logit > 0.5
    bool fgT = edge_at(pt + b * HW, i, q, c);                            // targ = et*c > 0.5 <=> et

    unsigned long long bP = __ballot((int)fgP);
    unsigned long long bT = __ballot((int)fgT);
    int lane = i & 63, w = i >> 6;
    if (lane == 0) {
        if (w == 0) { cbP[blk].x = bP; cbT[blk].x = bT; }
        else        { cbP[blk].y = bP; cbT[blk].y = bT; }
        int fl = (bP ? 1 : 0) | (bP != ~0ULL ? 2 : 0)
               | (bT ? 4 : 0) | (bT != ~0ULL ? 8 : 0);
        atomicOr(&flags[n], fl);
    }
}

// fused: 1D column EDT (bit-trick) -> row EDT (q loop) -> loss accumulation.
// block = (pair n, row i), 128 threads = j.
__global__ void k_C(const unsigned char* __restrict__ ps, const unsigned char* __restrict__ pt,
                    const float* __restrict__ Ls,
                    const ulonglong2* __restrict__ cbP, const ulonglong2* __restrict__ cbT,
                    const int* __restrict__ flags, float* __restrict__ sums) {
    int n = blockIdx.x >> 7, i = blockIdx.x & (HH - 1);
    int j = threadIdx.x;
    int b = n / (CC - 1), c = 1 + (n - b * (CC - 1));

    __shared__ int4 sq[WW];        // per-column d1^2 for {fgP, bgP, fgT, bgT}
    ulonglong2 mP = cbP[n * WW + j];
    ulonglong2 mT = cbT[n * WW + j];
    int dP  = nbd(mP.x, mP.y, i);
    int dPb = nbd(~mP.x, ~mP.y, i);
    int dT  = nbd(mT.x, mT.y, i);
    int dTb = nbd(~mT.x, ~mT.y, i);
    sq[j] = make_int4(dP * dP, dPb * dPb, dT * dT, dTb * dTb);
    __syncthreads();

    int b0 = INT_MAX, b1 = INT_MAX, b2 = INT_MAX, b3 = INT_MAX;
#pragma unroll 4
    for (int q = 0; q < WW; ++q) {
        int4 s = sq[q];
        int dq = q - j;
        int off = dq * dq;
        b0 = min(b0, s.x + off);
        b1 = min(b1, s.y + off);
        b2 = min(b2, s.z + off);
        b3 = min(b3, s.w + off);
    }

    int f = flags[n];
    float fieldP = ((f & 3)  == 3)  ? (float)(b0 + b1) : 0.0f;
    float fieldT = ((f & 12) == 12) ? (float)(b2 + b3) : 0.0f;

    bool es = edge_at(ps + b * HW, i, j, c);
    float predv = 0.0f;
    if (es) predv = Ls[((size_t)(b * CC + c)) * HW + i * WW + j];
    bool et = edge_at(pt + b * HW, i, j, c);
    float targv = et ? (float)c : 0.0f;
    float diff = predv - targv;
    float v = diff * diff * (fieldP + fieldT);

    for (int o = 32; o > 0; o >>= 1) v += __shfl_down(v, o);
    __shared__ float wsum[2];
    int lane = j & 63, w = j >> 6;
    if (lane == 0) wsum[w] = v;
    __syncthreads();
    if (j == 0) atomicAdd(&sums[n], wsum[0] + wsum[1]);
}

__global__ void k_final(const float* __restrict__ sums, float* __restrict__ out) {
    if (blockIdx.x == 0 && threadIdx.x == 0) {
        float s = 0.0f;
        for (int n = 0; n < NPAIR; ++n) {
            float hd = sums[n] * (1.0f / (float)HW);
            s += logf(hd + 1.0f);
        }
        out[0] = 0.5f * s;   // (1 - LOSS_WEIGHT) * sum
    }
}

extern "C" void kernel_launch(void* const* d_in, const int* in_sizes, int n_in,
                              void* d_out, int out_size, void* d_ws, size_t ws_size,
                              hipStream_t stream) {
    const float* Ls = (const float*)d_in[0];
    const float* Lt = (const float*)d_in[1];
    float* out = (float*)d_out;

    char* w = (char*)d_ws;
    unsigned char* ps    = (unsigned char*)(w);
    unsigned char* pt    = (unsigned char*)(w + 32768);
    ulonglong2*    cbP   = (ulonglong2*)   (w + 65536);
    ulonglong2*    cbT   = (ulonglong2*)   (w + 118784);
    int*           flags = (int*)          (w + 172032);
    float*         sums  = (float*)        (w + 172160);

    k_argmax<<<(2 * BB * HW + 255) / 256, 256, 0, stream>>>(Ls, Lt, ps, pt, flags, sums);
    k_bits<<<NPAIR * WW, HH, 0, stream>>>(ps, pt, Ls, cbP, cbT, flags);
    k_C<<<NPAIR * HH, WW, 0, stream>>>(ps, pt, Ls, cbP, cbT, flags, sums);
    k_final<<<1, 64, 0, stream>>>(sums, out);
}

// Round 3
// 136.274 us; speedup vs baseline: 1.1171x; 1.0767x over previous
//
#include <hip/hip_runtime.h>
#include <math.h>
#include <limits.h>

#define HH 128
#define WW 128
#define HW (HH*WW)
#define BB 2
#define CC 14
#define NPAIR 26   // B * (C-1)

typedef unsigned long long u64;

// ---------------------------------------------------------------------------
// ws layout (bytes):
//   ps    : [BB][HW] u8        @ 0        (32768)
//   pt    : [BB][HW] u8        @ 32768    (32768)
//   cbP   : [NPAIR][WW] u64x2  @ 65536    (53248)  fgP column masks (es & logit>0.5)
//   cbT   : [NPAIR][WW] u64x2  @ 118784   (53248)  fgT column masks (= teacher edge)
//   esC   : [NPAIR][WW] u64x2  @ 172032   (53248)  student edge column masks
//   flags : [NPAIR] int        @ 225280   (104)    bit0 anyFgP,1 anyBgP,2 anyFgT,3 anyBgT
//   sums  : [NPAIR] f32        @ 225408   (104)
// ---------------------------------------------------------------------------

// distance from row i to nearest set bit in 128-bit mask {lo,hi}; 255 if empty.
// i is block-uniform in k_C -> uniform branches.
__device__ inline int nbd(u64 lo, u64 hi, int i) {
    int up = 255, down = 255;
    u64 slo, shi;
    if (i == 0)      { slo = lo; shi = hi; }
    else if (i < 64) { slo = (lo >> i) | (hi << (64 - i)); shi = hi >> i; }
    else             { slo = hi >> (i - 64); shi = 0ULL; }
    if (slo)      up = __builtin_ctzll(slo);
    else if (shi) up = 64 + __builtin_ctzll(shi);
    int s = 127 - i;
    u64 llo, lhi;
    if (s == 0)      { llo = lo; lhi = hi; }
    else if (s < 64) { lhi = (hi << s) | (lo >> (64 - s)); llo = lo << s; }
    else             { lhi = lo << (s - 64); llo = 0ULL; }
    if (lhi)      down = __builtin_clzll(lhi);
    else if (llo) down = 64 + __builtin_clzll(llo);
    return min(up, down);
}

// argmax over channels for student+teacher; block 0 also zeroes flags/sums
__global__ void k_argmax(const float* __restrict__ Ls, const float* __restrict__ Lt,
                         unsigned char* __restrict__ ps, unsigned char* __restrict__ pt,
                         int* __restrict__ flags, float* __restrict__ sums) {
    if (blockIdx.x == 0 && threadIdx.x < NPAIR) {
        flags[threadIdx.x] = 0;
        sums[threadIdx.x] = 0.0f;
    }
    int tid = blockIdx.x * blockDim.x + threadIdx.x;
    const int total = BB * HW;
    if (tid >= 2 * total) return;
    const float* L = (tid < total) ? Ls : Lt;
    unsigned char* dst = (tid < total) ? ps : pt;
    int p = (tid < total) ? tid : tid - total;
    int b = p / HW;
    int pix = p - b * HW;
    const float* base = L + (size_t)b * CC * HW + pix;
    float best = base[0];
    int bi = 0;
#pragma unroll
    for (int c = 1; c < CC; ++c) {
        float v = base[(size_t)c * HW];
        if (v > best) { best = v; bi = c; }   // first-max tie rule
    }
    dst[p] = (unsigned char)bi;
}

// per-pair column bitmask build + bit-parallel edge masks.
// block = pair n; 128 threads = columns j. All global reads coalesced.
__global__ void k_prep(const unsigned char* __restrict__ ps, const unsigned char* __restrict__ pt,
                       const float* __restrict__ Ls,
                       ulonglong2* __restrict__ cbP, ulonglong2* __restrict__ cbT,
                       ulonglong2* __restrict__ esC, int* __restrict__ flags) {
    int n = blockIdx.x;
    int j = threadIdx.x;
    int b = n / (CC - 1), c = 1 + (n - b * (CC - 1));
    const unsigned char* P = ps + b * HW;
    const unsigned char* T = pt + b * HW;
    const float* Lp = Ls + (size_t)(b * CC + c) * HW;

    u64 ms0 = 0, ms1 = 0, mt0 = 0, mt1 = 0, hi0 = 0, hi1 = 0;
#pragma unroll 8
    for (int i = 0; i < HH; ++i) {
        int off = i * WW + j;
        u64 bit = 1ull << (i & 63);
        bool s = (P[off] == c);
        bool t = (T[off] == c);
        bool h = (Lp[off] > 0.5f);
        if (i < 64) { if (s) ms0 |= bit; if (t) mt0 |= bit; if (h) hi0 |= bit; }
        else        { if (s) ms1 |= bit; if (t) mt1 |= bit; if (h) hi1 |= bit; }
    }

    __shared__ ulonglong2 sS[WW], sT[WW];
    sS[j] = make_ulonglong2(ms0, ms1);
    sT[j] = make_ulonglong2(mt0, mt1);
    __syncthreads();
    ulonglong2 z = make_ulonglong2(0ull, 0ull);
    ulonglong2 Ls_ = (j > 0)      ? sS[j - 1] : z;
    ulonglong2 Rs_ = (j < WW - 1) ? sS[j + 1] : z;
    ulonglong2 Lt_ = (j > 0)      ? sT[j - 1] : z;
    ulonglong2 Rt_ = (j < WW - 1) ? sT[j + 1] : z;

    // erosion: m & up(m) & down(m) & left & right; shifts insert 0 (border erodes)
    u64 U0 = ms0 << 1, U1 = (ms1 << 1) | (ms0 >> 63);
    u64 D0 = (ms0 >> 1) | (ms1 << 63), D1 = ms1 >> 1;
    u64 er0 = ms0 & U0 & D0 & Ls_.x & Rs_.x;
    u64 er1 = ms1 & U1 & D1 & Ls_.y & Rs_.y;
    u64 es0 = ms0 & ~er0, es1 = ms1 & ~er1;

    u64 Ut0 = mt0 << 1, Ut1 = (mt1 << 1) | (mt0 >> 63);
    u64 Dt0 = (mt0 >> 1) | (mt1 << 63), Dt1 = mt1 >> 1;
    u64 ert0 = mt0 & Ut0 & Dt0 & Lt_.x & Rt_.x;
    u64 ert1 = mt1 & Ut1 & Dt1 & Lt_.y & Rt_.y;
    u64 et0 = mt0 & ~ert0, et1 = mt1 & ~ert1;

    u64 fp0 = es0 & hi0, fp1 = es1 & hi1;   // pred = es*logit > 0.5

    int idx = n * WW + j;
    cbP[idx] = make_ulonglong2(fp0, fp1);
    cbT[idx] = make_ulonglong2(et0, et1);
    esC[idx] = make_ulonglong2(es0, es1);

    u64 bFgP = __ballot((fp0 | fp1) != 0ull);
    u64 bBgP = __ballot((fp0 & fp1) != ~0ull);
    u64 bFgT = __ballot((et0 | et1) != 0ull);
    u64 bBgT = __ballot((et0 & et1) != ~0ull);
    if ((j & 63) == 0) {
        int fl = (bFgP ? 1 : 0) | (bBgP ? 2 : 0) | (bFgT ? 4 : 0) | (bBgT ? 8 : 0);
        atomicOr(&flags[n], fl);
    }
}

// fused: column EDT (bit-trick) -> row EDT (q loop) -> loss accumulation.
// block = (pair n, row i), 128 threads = j.
__global__ void k_C(const float* __restrict__ Ls,
                    const ulonglong2* __restrict__ cbP, const ulonglong2* __restrict__ cbT,
                    const ulonglong2* __restrict__ esC,
                    const int* __restrict__ flags, float* __restrict__ sums) {
    int n = blockIdx.x >> 7, i = blockIdx.x & (HH - 1);
    int j = threadIdx.x;
    int b = n / (CC - 1), c = 1 + (n - b * (CC - 1));

    __shared__ int4 sq[WW];
    int idx = n * WW + j;
    ulonglong2 mP = cbP[idx];
    ulonglong2 mT = cbT[idx];
    ulonglong2 eS = esC[idx];
    int dP  = nbd(mP.x, mP.y, i);
    int dPb = nbd(~mP.x, ~mP.y, i);
    int dT  = nbd(mT.x, mT.y, i);
    int dTb = nbd(~mT.x, ~mT.y, i);
    sq[j] = make_int4(dP * dP, dPb * dPb, dT * dT, dTb * dTb);
    __syncthreads();

    int b0 = INT_MAX, b1 = INT_MAX, b2 = INT_MAX, b3 = INT_MAX;
#pragma unroll 4
    for (int q = 0; q < WW; ++q) {
        int4 s = sq[q];
        int dq = q - j;
        int off = dq * dq;
        b0 = min(b0, s.x + off);
        b1 = min(b1, s.y + off);
        b2 = min(b2, s.z + off);
        b3 = min(b3, s.w + off);
    }

    int f = flags[n];
    float fieldP = ((f & 3)  == 3)  ? (float)(b0 + b1) : 0.0f;
    float fieldT = ((f & 12) == 12) ? (float)(b2 + b3) : 0.0f;

    bool es = ((i < 64 ? (eS.x >> i) : (eS.y >> (i - 64))) & 1ull) != 0;
    bool et = ((i < 64 ? (mT.x >> i) : (mT.y >> (i - 64))) & 1ull) != 0;
    float lv = Ls[(size_t)(b * CC + c) * HW + i * WW + j];  // coalesced
    float predv = es ? lv : 0.0f;
    float targv = et ? (float)c : 0.0f;
    float diff = predv - targv;
    float v = diff * diff * (fieldP + fieldT);

    for (int o = 32; o > 0; o >>= 1) v += __shfl_down(v, o);
    __shared__ float wsum[2];
    int lane = j & 63, w = j >> 6;
    if (lane == 0) wsum[w] = v;
    __syncthreads();
    if (j == 0) atomicAdd(&sums[n], wsum[0] + wsum[1]);
}

__global__ void k_final(const float* __restrict__ sums, float* __restrict__ out) {
    int t = threadIdx.x;
    float v = 0.0f;
    if (t < NPAIR) {
        float hd = sums[t] * (1.0f / (float)HW);
        v = logf(hd + 1.0f);
    }
    for (int o = 32; o > 0; o >>= 1) v += __shfl_down(v, o);
    if (t == 0) out[0] = 0.5f * v;   // (1 - LOSS_WEIGHT) * sum
}

extern "C" void kernel_launch(void* const* d_in, const int* in_sizes, int n_in,
                              void* d_out, int out_size, void* d_ws, size_t ws_size,
                              hipStream_t stream) {
    const float* Ls = (const float*)d_in[0];
    const float* Lt = (const float*)d_in[1];
    float* out = (float*)d_out;

    char* w = (char*)d_ws;
    unsigned char* ps    = (unsigned char*)(w);
    unsigned char* pt    = (unsigned char*)(w + 32768);
    ulonglong2*    cbP   = (ulonglong2*)   (w + 65536);
    ulonglong2*    cbT   = (ulonglong2*)   (w + 118784);
    ulonglong2*    esC   = (ulonglong2*)   (w + 172032);
    int*           flags = (int*)          (w + 225280);
    float*         sums  = (float*)        (w + 225408);

    k_argmax<<<(2 * BB * HW + 255) / 256, 256, 0, stream>>>(Ls, Lt, ps, pt, flags, sums);
    k_prep<<<NPAIR, WW, 0, stream>>>(ps, pt, Ls, cbP, cbT, esC, flags);
    k_C<<<NPAIR * HH, WW, 0, stream>>>(Ls, cbP, cbT, esC, flags, sums);
    k_final<<<1, 64, 0, stream>>>(sums, out);
}

// Round 4
// 135.293 us; speedup vs baseline: 1.1252x; 1.0073x over previous
//
#include <hip/hip_runtime.h>
#include <math.h>
#include <limits.h>

#define HH 128
#define WW 128
#define HW (HH*WW)
#define BB 2
#define CC 14
#define NPAIR 26   // B * (C-1)

typedef unsigned long long u64;

// ---------------------------------------------------------------------------
// ws layout (bytes):
//   ps    : [BB][HW] u8        @ 0        (32768)
//   pt    : [BB][HW] u8        @ 32768    (32768)
//   cbP   : [NPAIR][WW] u64x2  @ 65536    (53248)  fgP column masks (es & logit>0.5)
//   cbT   : [NPAIR][WW] u64x2  @ 118784   (53248)  fgT column masks (= teacher edge)
//   esC   : [NPAIR][WW] u64x2  @ 172032   (53248)  student edge column masks
//   flags : [NPAIR] int        @ 225280   (104)    bit0 anyFgP,1 anyBgP,2 anyFgT,3 anyBgT
//   sums  : [NPAIR] f32        @ 225408   (104)
//   done  : int                @ 225536   (4)      last-block ticket
// ---------------------------------------------------------------------------

// distance from row i to nearest set bit in 128-bit mask {lo,hi}; 255 if empty.
// i is block-uniform in k_C -> uniform branches.
__device__ inline int nbd(u64 lo, u64 hi, int i) {
    int up = 255, down = 255;
    u64 slo, shi;
    if (i == 0)      { slo = lo; shi = hi; }
    else if (i < 64) { slo = (lo >> i) | (hi << (64 - i)); shi = hi >> i; }
    else             { slo = hi >> (i - 64); shi = 0ULL; }
    if (slo)      up = __builtin_ctzll(slo);
    else if (shi) up = 64 + __builtin_ctzll(shi);
    int s = 127 - i;
    u64 llo, lhi;
    if (s == 0)      { llo = lo; lhi = hi; }
    else if (s < 64) { lhi = (hi << s) | (lo >> (64 - s)); llo = lo << s; }
    else             { lhi = lo << (s - 64); llo = 0ULL; }
    if (lhi)      down = __builtin_clzll(lhi);
    else if (llo) down = 64 + __builtin_clzll(llo);
    return min(up, down);
}

// argmax over channels, 4 pixels/thread (float4). block 0 zeroes flags/sums/done.
__global__ void k_argmax(const float* __restrict__ Ls, const float* __restrict__ Lt,
                         unsigned char* __restrict__ ps, unsigned char* __restrict__ pt,
                         int* __restrict__ flags, float* __restrict__ sums,
                         int* __restrict__ done) {
    if (blockIdx.x == 0) {
        if (threadIdx.x < NPAIR) { flags[threadIdx.x] = 0; sums[threadIdx.x] = 0.0f; }
        if (threadIdx.x == 0) *done = 0;
    }
    int tid = blockIdx.x * blockDim.x + threadIdx.x;
    const int total4 = BB * HW / 4;           // 8192 float4-groups per tensor
    if (tid >= 2 * total4) return;
    const float* L; unsigned char* dst; int p4;
    if (tid < total4) { L = Ls; dst = ps; p4 = tid; }
    else              { L = Lt; dst = pt; p4 = tid - total4; }
    int b = p4 / (HW / 4);
    int q4 = p4 - b * (HW / 4);
    const float4* base = (const float4*)(L + (size_t)b * CC * HW) + q4;
    float4 best = base[0];
    uchar4 bi = make_uchar4(0, 0, 0, 0);
#pragma unroll
    for (int c = 1; c < CC; ++c) {
        float4 v = base[(size_t)c * (HW / 4)];
        if (v.x > best.x) { best.x = v.x; bi.x = (unsigned char)c; }
        if (v.y > best.y) { best.y = v.y; bi.y = (unsigned char)c; }
        if (v.z > best.z) { best.z = v.z; bi.z = (unsigned char)c; }
        if (v.w > best.w) { best.w = v.w; bi.w = (unsigned char)c; }
    }
    ((uchar4*)dst)[b * (HW / 4) + q4] = bi;
}

__device__ inline u64 asm64(unsigned int (*p)[WW], int k0, int j) {
    return (u64)p[k0][j] | ((u64)p[k0 + 1][j] << 16)
         | ((u64)p[k0 + 2][j] << 32) | ((u64)p[k0 + 3][j] << 48);
}

// per-pair column bitmask build + bit-parallel edge masks.
// block = pair n; 1024 threads = (row-chunk k of 16 rows, column j).
__global__ __launch_bounds__(1024) void k_prep(
        const unsigned char* __restrict__ ps, const unsigned char* __restrict__ pt,
        const float* __restrict__ Ls,
        ulonglong2* __restrict__ cbP, ulonglong2* __restrict__ cbT,
        ulonglong2* __restrict__ esC, int* __restrict__ flags) {
    int n = blockIdx.x;
    int tid = threadIdx.x;
    int k = tid >> 7;          // 0..7
    int j = tid & (WW - 1);
    int b = n / (CC - 1), c = 1 + (n - b * (CC - 1));
    const unsigned char* P = ps + b * HW;
    const unsigned char* T = pt + b * HW;
    const float* Lp = Ls + (size_t)(b * CC + c) * HW;

    unsigned int s16 = 0, t16 = 0, h16 = 0;
    int i0 = k << 4;
#pragma unroll
    for (int r = 0; r < 16; ++r) {
        int off = (i0 + r) * WW + j;         // coalesced across j
        if (P[off] == c)      s16 |= 1u << r;
        if (T[off] == c)      t16 |= 1u << r;
        if (Lp[off] > 0.5f)   h16 |= 1u << r;
    }
    __shared__ unsigned int pS[8][WW], pT[8][WW], pH[8][WW];
    pS[k][j] = s16; pT[k][j] = t16; pH[k][j] = h16;
    __syncthreads();

    if (tid < WW) {
        u64 ms0 = asm64(pS, 0, j), ms1 = asm64(pS, 4, j);
        u64 mt0 = asm64(pT, 0, j), mt1 = asm64(pT, 4, j);
        u64 hi0 = asm64(pH, 0, j), hi1 = asm64(pH, 4, j);
        u64 Lsx = 0, Lsy = 0, Ltx = 0, Lty = 0, Rsx = 0, Rsy = 0, Rtx = 0, Rty = 0;
        if (j > 0)      { Lsx = asm64(pS, 0, j - 1); Lsy = asm64(pS, 4, j - 1);
                          Ltx = asm64(pT, 0, j - 1); Lty = asm64(pT, 4, j - 1); }
        if (j < WW - 1) { Rsx = asm64(pS, 0, j + 1); Rsy = asm64(pS, 4, j + 1);
                          Rtx = asm64(pT, 0, j + 1); Rty = asm64(pT, 4, j + 1); }

        // erosion: m & up & down & left & right; shifts insert 0 (border erodes)
        u64 U0 = ms0 << 1, U1 = (ms1 << 1) | (ms0 >> 63);
        u64 D0 = (ms0 >> 1) | (ms1 << 63), D1 = ms1 >> 1;
        u64 er0 = ms0 & U0 & D0 & Lsx & Rsx;
        u64 er1 = ms1 & U1 & D1 & Lsy & Rsy;
        u64 es0 = ms0 & ~er0, es1 = ms1 & ~er1;

        u64 Ut0 = mt0 << 1, Ut1 = (mt1 << 1) | (mt0 >> 63);
        u64 Dt0 = (mt0 >> 1) | (mt1 << 63), Dt1 = mt1 >> 1;
        u64 ert0 = mt0 & Ut0 & Dt0 & Ltx & Rtx;
        u64 ert1 = mt1 & Ut1 & Dt1 & Lty & Rty;
        u64 et0 = mt0 & ~ert0, et1 = mt1 & ~ert1;

        u64 fp0 = es0 & hi0, fp1 = es1 & hi1;   // pred = es*logit > 0.5

        int idx = n * WW + j;
        cbP[idx] = make_ulonglong2(fp0, fp1);
        cbT[idx] = make_ulonglong2(et0, et1);
        esC[idx] = make_ulonglong2(es0, es1);

        u64 bFgP = __ballot((fp0 | fp1) != 0ull);
        u64 bBgP = __ballot((fp0 & fp1) != ~0ull);
        u64 bFgT = __ballot((et0 | et1) != 0ull);
        u64 bBgT = __ballot((et0 & et1) != ~0ull);
        if ((j & 63) == 0) {
            int fl = (bFgP ? 1 : 0) | (bBgP ? 2 : 0) | (bFgT ? 4 : 0) | (bBgT ? 8 : 0);
            atomicOr(&flags[n], fl);
        }
    }
}

// fused: column EDT (bit-trick) -> row EDT (q loop) -> loss accumulation ->
// last-block final log reduction. block = (pair n, row i), 128 threads = j.
__global__ void k_C(const float* __restrict__ Ls,
                    const ulonglong2* __restrict__ cbP, const ulonglong2* __restrict__ cbT,
                    const ulonglong2* __restrict__ esC,
                    const int* __restrict__ flags, float* __restrict__ sums,
                    int* __restrict__ done, float* __restrict__ out) {
    int n = blockIdx.x >> 7, i = blockIdx.x & (HH - 1);
    int j = threadIdx.x;
    int b = n / (CC - 1), c = 1 + (n - b * (CC - 1));

    __shared__ int4 sq[WW];
    int idx = n * WW + j;
    ulonglong2 mP = cbP[idx];
    ulonglong2 mT = cbT[idx];
    ulonglong2 eS = esC[idx];
    int dP  = nbd(mP.x, mP.y, i);
    int dPb = nbd(~mP.x, ~mP.y, i);
    int dT  = nbd(mT.x, mT.y, i);
    int dTb = nbd(~mT.x, ~mT.y, i);
    sq[j] = make_int4(dP * dP, dPb * dPb, dT * dT, dTb * dTb);
    __syncthreads();

    int b0 = INT_MAX, b1 = INT_MAX, b2 = INT_MAX, b3 = INT_MAX;
#pragma unroll 4
    for (int q = 0; q < WW; ++q) {
        int4 s = sq[q];
        int dq = q - j;
        int off = dq * dq;
        b0 = min(b0, s.x + off);
        b1 = min(b1, s.y + off);
        b2 = min(b2, s.z + off);
        b3 = min(b3, s.w + off);
    }

    int f = flags[n];
    float fieldP = ((f & 3)  == 3)  ? (float)(b0 + b1) : 0.0f;
    float fieldT = ((f & 12) == 12) ? (float)(b2 + b3) : 0.0f;

    bool es = ((i < 64 ? (eS.x >> i) : (eS.y >> (i - 64))) & 1ull) != 0;
    bool et = ((i < 64 ? (mT.x >> i) : (mT.y >> (i - 64))) & 1ull) != 0;
    float lv = Ls[(size_t)(b * CC + c) * HW + i * WW + j];  // coalesced
    float predv = es ? lv : 0.0f;
    float targv = et ? (float)c : 0.0f;
    float diff = predv - targv;
    float v = diff * diff * (fieldP + fieldT);

    for (int o = 32; o > 0; o >>= 1) v += __shfl_down(v, o);
    __shared__ float wsum[2];
    int lane = j & 63, w = j >> 6;
    if (lane == 0) wsum[w] = v;
    __syncthreads();
    if (j == 0) {
        atomicAdd(&sums[n], wsum[0] + wsum[1]);
        __threadfence();                       // sums visible before ticket
        int t = atomicAdd(done, 1);
        if (t == (int)gridDim.x - 1) {         // dynamically last block
            float s = 0.0f;
            for (int m = 0; m < NPAIR; ++m) {
                float hd = atomicAdd(&sums[m], 0.0f) * (1.0f / (float)HW); // L2 read
                s += logf(hd + 1.0f);
            }
            out[0] = 0.5f * s;                 // (1 - LOSS_WEIGHT) * sum
        }
    }
}

extern "C" void kernel_launch(void* const* d_in, const int* in_sizes, int n_in,
                              void* d_out, int out_size, void* d_ws, size_t ws_size,
                              hipStream_t stream) {
    const float* Ls = (const float*)d_in[0];
    const float* Lt = (const float*)d_in[1];
    float* out = (float*)d_out;

    char* w = (char*)d_ws;
    unsigned char* ps    = (unsigned char*)(w);
    unsigned char* pt    = (unsigned char*)(w + 32768);
    ulonglong2*    cbP   = (ulonglong2*)   (w + 65536);
    ulonglong2*    cbT   = (ulonglong2*)   (w + 118784);
    ulonglong2*    esC   = (ulonglong2*)   (w + 172032);
    int*           flags = (int*)          (w + 225280);
    float*         sums  = (float*)        (w + 225408);
    int*           done  = (int*)          (w + 225536);

    k_argmax<<<(2 * BB * HW / 4 + 255) / 256, 256, 0, stream>>>(Ls, Lt, ps, pt, flags, sums, done);
    k_prep<<<NPAIR, 1024, 0, stream>>>(ps, pt, Ls, cbP, cbT, esC, flags);
    k_C<<<NPAIR * HH, WW, 0, stream>>>(Ls, cbP, cbT, esC, flags, sums, done, out);
}

// Round 5
// 79.435 us; speedup vs baseline: 1.9164x; 1.7032x over previous
//
#include <hip/hip_runtime.h>
#include <math.h>
#include <limits.h>

#define HH 128
#define WW 128
#define HW (HH*WW)
#define BB 2
#define CC 14
#define NPAIR 26   // B * (C-1)
#define RPB 4                      // rows per k_C block
#define NBLK (NPAIR * (HH / RPB))  // 832 k_C blocks

typedef unsigned long long u64;

// ---------------------------------------------------------------------------
// ws layout (bytes):
//   ps    : [BB][HW] u8        @ 0        (32768)
//   pt    : [BB][HW] u8        @ 32768    (32768)
//   cbP   : [NPAIR][WW] u64x2  @ 65536    (53248)  fgP column masks (es & logit>0.5)
//   cbT   : [NPAIR][WW] u64x2  @ 118784   (53248)  fgT column masks (= teacher edge)
//   esC   : [NPAIR][WW] u64x2  @ 172032   (53248)  student edge column masks
//   flags : [NPAIR] int        @ 225280   (104)    bit0 anyFgP,1 anyBgP,2 anyFgT,3 anyBgT
//   sums  : [NPAIR] f32        @ 225408   (104)
//   done  : int                @ 225536   (4)      last-block ticket
// ---------------------------------------------------------------------------

// distance from row i to nearest set bit in 128-bit mask {lo,hi}; 255 if empty.
// i is wave-uniform in k_C -> uniform branches.
__device__ inline int nbd(u64 lo, u64 hi, int i) {
    int up = 255, down = 255;
    u64 slo, shi;
    if (i == 0)      { slo = lo; shi = hi; }
    else if (i < 64) { slo = (lo >> i) | (hi << (64 - i)); shi = hi >> i; }
    else             { slo = hi >> (i - 64); shi = 0ULL; }
    if (slo)      up = __builtin_ctzll(slo);
    else if (shi) up = 64 + __builtin_ctzll(shi);
    int s = 127 - i;
    u64 llo, lhi;
    if (s == 0)      { llo = lo; lhi = hi; }
    else if (s < 64) { lhi = (hi << s) | (lo >> (64 - s)); llo = lo << s; }
    else             { lhi = lo << (s - 64); llo = 0ULL; }
    if (lhi)      down = __builtin_clzll(lhi);
    else if (llo) down = 64 + __builtin_clzll(llo);
    return min(up, down);
}

// argmax over channels, 4 pixels/thread (float4). block 0 zeroes flags/sums/done.
__global__ void k_argmax(const float* __restrict__ Ls, const float* __restrict__ Lt,
                         unsigned char* __restrict__ ps, unsigned char* __restrict__ pt,
                         int* __restrict__ flags, float* __restrict__ sums,
                         int* __restrict__ done) {
    if (blockIdx.x == 0) {
        if (threadIdx.x < NPAIR) { flags[threadIdx.x] = 0; sums[threadIdx.x] = 0.0f; }
        if (threadIdx.x == 0) *done = 0;
    }
    int tid = blockIdx.x * blockDim.x + threadIdx.x;
    const int total4 = BB * HW / 4;
    if (tid >= 2 * total4) return;
    const float* L; unsigned char* dst; int p4;
    if (tid < total4) { L = Ls; dst = ps; p4 = tid; }
    else              { L = Lt; dst = pt; p4 = tid - total4; }
    int b = p4 / (HW / 4);
    int q4 = p4 - b * (HW / 4);
    const float4* base = (const float4*)(L + (size_t)b * CC * HW) + q4;
    float4 best = base[0];
    uchar4 bi = make_uchar4(0, 0, 0, 0);
#pragma unroll
    for (int c = 1; c < CC; ++c) {
        float4 v = base[(size_t)c * (HW / 4)];
        if (v.x > best.x) { best.x = v.x; bi.x = (unsigned char)c; }
        if (v.y > best.y) { best.y = v.y; bi.y = (unsigned char)c; }
        if (v.z > best.z) { best.z = v.z; bi.z = (unsigned char)c; }
        if (v.w > best.w) { best.w = v.w; bi.w = (unsigned char)c; }
    }
    ((uchar4*)dst)[b * (HW / 4) + q4] = bi;
}

__device__ inline u64 asm64(unsigned int (*p)[WW], int k0, int j) {
    return (u64)p[k0][j] | ((u64)p[k0 + 1][j] << 16)
         | ((u64)p[k0 + 2][j] << 32) | ((u64)p[k0 + 3][j] << 48);
}

// per-pair column bitmask build + bit-parallel edge masks.
// block = pair n; 1024 threads = (row-chunk k of 16 rows, column j).
__global__ __launch_bounds__(1024) void k_prep(
        const unsigned char* __restrict__ ps, const unsigned char* __restrict__ pt,
        const float* __restrict__ Ls,
        ulonglong2* __restrict__ cbP, ulonglong2* __restrict__ cbT,
        ulonglong2* __restrict__ esC, int* __restrict__ flags) {
    int n = blockIdx.x;
    int tid = threadIdx.x;
    int k = tid >> 7;          // 0..7
    int j = tid & (WW - 1);
    int b = n / (CC - 1), c = 1 + (n - b * (CC - 1));
    const unsigned char* P = ps + b * HW;
    const unsigned char* T = pt + b * HW;
    const float* Lp = Ls + (size_t)(b * CC + c) * HW;

    unsigned int s16 = 0, t16 = 0, h16 = 0;
    int i0 = k << 4;
#pragma unroll
    for (int r = 0; r < 16; ++r) {
        int off = (i0 + r) * WW + j;         // coalesced across j
        if (P[off] == c)      s16 |= 1u << r;
        if (T[off] == c)      t16 |= 1u << r;
        if (Lp[off] > 0.5f)   h16 |= 1u << r;
    }
    __shared__ unsigned int pS[8][WW], pT[8][WW], pH[8][WW];
    pS[k][j] = s16; pT[k][j] = t16; pH[k][j] = h16;
    __syncthreads();

    if (tid < WW) {
        u64 ms0 = asm64(pS, 0, j), ms1 = asm64(pS, 4, j);
        u64 mt0 = asm64(pT, 0, j), mt1 = asm64(pT, 4, j);
        u64 hi0 = asm64(pH, 0, j), hi1 = asm64(pH, 4, j);
        u64 Lsx = 0, Lsy = 0, Ltx = 0, Lty = 0, Rsx = 0, Rsy = 0, Rtx = 0, Rty = 0;
        if (j > 0)      { Lsx = asm64(pS, 0, j - 1); Lsy = asm64(pS, 4, j - 1);
                          Ltx = asm64(pT, 0, j - 1); Lty = asm64(pT, 4, j - 1); }
        if (j < WW - 1) { Rsx = asm64(pS, 0, j + 1); Rsy = asm64(pS, 4, j + 1);
                          Rtx = asm64(pT, 0, j + 1); Rty = asm64(pT, 4, j + 1); }

        // erosion: m & up & down & left & right; shifts insert 0 (border erodes)
        u64 U0 = ms0 << 1, U1 = (ms1 << 1) | (ms0 >> 63);
        u64 D0 = (ms0 >> 1) | (ms1 << 63), D1 = ms1 >> 1;
        u64 er0 = ms0 & U0 & D0 & Lsx & Rsx;
        u64 er1 = ms1 & U1 & D1 & Lsy & Rsy;
        u64 es0 = ms0 & ~er0, es1 = ms1 & ~er1;

        u64 Ut0 = mt0 << 1, Ut1 = (mt1 << 1) | (mt0 >> 63);
        u64 Dt0 = (mt0 >> 1) | (mt1 << 63), Dt1 = mt1 >> 1;
        u64 ert0 = mt0 & Ut0 & Dt0 & Ltx & Rtx;
        u64 ert1 = mt1 & Ut1 & Dt1 & Lty & Rty;
        u64 et0 = mt0 & ~ert0, et1 = mt1 & ~ert1;

        u64 fp0 = es0 & hi0, fp1 = es1 & hi1;   // pred = es*logit > 0.5

        int idx = n * WW + j;
        cbP[idx] = make_ulonglong2(fp0, fp1);
        cbT[idx] = make_ulonglong2(et0, et1);
        esC[idx] = make_ulonglong2(es0, es1);

        u64 bFgP = __ballot((fp0 | fp1) != 0ull);
        u64 bBgP = __ballot((fp0 & fp1) != ~0ull);
        u64 bFgT = __ballot((et0 | et1) != 0ull);
        u64 bBgT = __ballot((et0 & et1) != ~0ull);
        if ((j & 63) == 0) {
            int fl = (bFgP ? 1 : 0) | (bBgP ? 2 : 0) | (bFgT ? 4 : 0) | (bBgT ? 8 : 0);
            atomicOr(&flags[n], fl);
        }
    }
}

// fused: column EDT (bit-trick) -> row EDT (early-exit expanding ring) ->
// loss accumulation -> last-block final reduction.
// block = (pair n, 4-row tile), 512 threads = (r, j).
__global__ __launch_bounds__(512) void k_C(
        const float* __restrict__ Ls,
        const ulonglong2* __restrict__ cbP, const ulonglong2* __restrict__ cbT,
        const ulonglong2* __restrict__ esC,
        const int* __restrict__ flags, float* __restrict__ sums,
        int* __restrict__ done, float* __restrict__ out) {
    int n = blockIdx.x >> 5;          // pair
    int t = blockIdx.x & 31;          // row tile
    int r = threadIdx.x >> 7;         // 0..3 (wave-uniform)
    int j = threadIdx.x & (WW - 1);
    int i = t * RPB + r;
    int b = n / (CC - 1), c = 1 + (n - b * (CC - 1));

    int idx = n * WW + j;
    ulonglong2 mP = cbP[idx];
    ulonglong2 mT = cbT[idx];
    ulonglong2 eS = esC[idx];
    int f = flags[n];
    bool aP = (f & 3) == 3, aT = (f & 12) == 12;

    int dP  = nbd(mP.x, mP.y, i);
    int dPb = nbd(~mP.x, ~mP.y, i);
    int dT  = nbd(mT.x, mT.y, i);
    int dTb = nbd(~mT.x, ~mT.y, i);

    __shared__ ushort4 sq[RPB][WW];   // d1^2 per map, u16 (max 65025 fits)
    sq[r][j] = make_ushort4((unsigned short)(dP * dP), (unsigned short)(dPb * dPb),
                            (unsigned short)(dT * dT), (unsigned short)(dTb * dTb));
    __syncthreads();

    int bP = dP * dP, bPb = dPb * dPb, bT = dT * dT, bTb = dTb * dTb;
    int need = 0;
    if (aP) need = max(bP, bPb);
    if (aT) need = max(need, max(bT, bTb));
    // expanding ring: candidates at radius rad are >= rad^2, so once
    // rad^2 >= need (best over maps we actually use), the min is final.
    for (int rad = 1; rad < WW; ++rad) {
        int rr = rad * rad;
        if (rr >= need) break;
        if (j >= rad) {
            ushort4 s = sq[r][j - rad];
            bP  = min(bP,  (int)s.x + rr); bPb = min(bPb, (int)s.y + rr);
            bT  = min(bT,  (int)s.z + rr); bTb = min(bTb, (int)s.w + rr);
        }
        if (j + rad < WW) {
            ushort4 s = sq[r][j + rad];
            bP  = min(bP,  (int)s.x + rr); bPb = min(bPb, (int)s.y + rr);
            bT  = min(bT,  (int)s.z + rr); bTb = min(bTb, (int)s.w + rr);
        }
        need = 0;
        if (aP) need = max(bP, bPb);
        if (aT) need = max(need, max(bT, bTb));
    }

    float fieldP = aP ? (float)(bP + bPb) : 0.0f;
    float fieldT = aT ? (float)(bT + bTb) : 0.0f;

    bool es = ((i < 64 ? (eS.x >> i) : (eS.y >> (i - 64))) & 1ull) != 0;
    bool et = ((i < 64 ? (mT.x >> i) : (mT.y >> (i - 64))) & 1ull) != 0;
    float lv = Ls[(size_t)(b * CC + c) * HW + i * WW + j];  // coalesced
    float predv = es ? lv : 0.0f;
    float targv = et ? (float)c : 0.0f;
    float diff = predv - targv;
    float v = diff * diff * (fieldP + fieldT);

    for (int o = 32; o > 0; o >>= 1) v += __shfl_down(v, o);
    __shared__ float wsum[8];
    __shared__ int won;
    int lane = threadIdx.x & 63, w = threadIdx.x >> 6;
    if (lane == 0) wsum[w] = v;
    if (threadIdx.x == 0) won = 0;
    __syncthreads();
    if (threadIdx.x == 0) {
        float tot = 0.0f;
#pragma unroll
        for (int k = 0; k < 8; ++k) tot += wsum[k];
        atomicAdd(&sums[n], tot);
        __threadfence();                       // sums visible before ticket
        if (atomicAdd(done, 1) == NBLK - 1) won = 1;
    }
    __syncthreads();
    if (won && threadIdx.x < 64) {             // wave 0 of the last block
        float vv = 0.0f;
        if (threadIdx.x < NPAIR) {
            float hd = atomicAdd(&sums[threadIdx.x], 0.0f) * (1.0f / (float)HW);
            vv = logf(hd + 1.0f);
        }
        for (int o = 32; o > 0; o >>= 1) vv += __shfl_down(vv, o);
        if (threadIdx.x == 0) out[0] = 0.5f * vv;   // (1 - LOSS_WEIGHT) * sum
    }
}

extern "C" void kernel_launch(void* const* d_in, const int* in_sizes, int n_in,
                              void* d_out, int out_size, void* d_ws, size_t ws_size,
                              hipStream_t stream) {
    const float* Ls = (const float*)d_in[0];
    const float* Lt = (const float*)d_in[1];
    float* out = (float*)d_out;

    char* w = (char*)d_ws;
    unsigned char* ps    = (unsigned char*)(w);
    unsigned char* pt    = (unsigned char*)(w + 32768);
    ulonglong2*    cbP   = (ulonglong2*)   (w + 65536);
    ulonglong2*    cbT   = (ulonglong2*)   (w + 118784);
    ulonglong2*    esC   = (ulonglong2*)   (w + 172032);
    int*           flags = (int*)          (w + 225280);
    float*         sums  = (float*)        (w + 225408);
    int*           done  = (int*)          (w + 225536);

    k_argmax<<<(2 * BB * HW / 4 + 255) / 256, 256, 0, stream>>>(Ls, Lt, ps, pt, flags, sums, done);
    k_prep<<<NPAIR, 1024, 0, stream>>>(ps, pt, Ls, cbP, cbT, esC, flags);
    k_C<<<NBLK, 512, 0, stream>>>(Ls, cbP, cbT, esC, flags, sums, done, out);
}